// Round 1
// baseline (234.280 us; speedup 1.0000x reference)
//
#include <hip/hip_runtime.h>
#include <cstdint>

#define L_DIM 2048
#define S_DIM 2048
#define E_DIM 1024
#define H_DIM 16
#define D_DIM 64

typedef __attribute__((ext_vector_type(4))) short short4v;
typedef __attribute__((ext_vector_type(8))) short short8v;
typedef __attribute__((ext_vector_type(4))) float f32x4;

__device__ __forceinline__ short f2bf(float f) {
  union { float f; uint32_t u; } v; v.f = f;
  uint32_t r = (v.u + 0x7fffu + ((v.u >> 16) & 1u)) >> 16;  // RNE
  return (short)(r & 0xffffu);
}

// ---------------- fp32 -> bf16 convert (q,k,v,in_proj_w,out_proj_w) ----------------
// Destinations are contiguous in ws, so one flat grid-stride-free kernel.
__global__ __launch_bounds__(256) void convert_all(
    const float* __restrict__ q, const float* __restrict__ k,
    const float* __restrict__ v, const float* __restrict__ win,
    const float* __restrict__ wout, short* __restrict__ dst)
{
  const int64_t i = (int64_t)blockIdx.x * 256 + threadIdx.x;  // vec4 index
  const int64_t NQ = (int64_t)L_DIM * E_DIM / 4;              // 524288
  const int64_t NW = (int64_t)3 * E_DIM * E_DIM / 4;          // 786432
  const float* src; int64_t off;
  if (i < NQ)               { src = q;    off = i; }
  else if (i < 2 * NQ)      { src = k;    off = i - NQ; }
  else if (i < 3 * NQ)      { src = v;    off = i - 2 * NQ; }
  else if (i < 3 * NQ + NW) { src = win;  off = i - 3 * NQ; }
  else                      { src = wout; off = i - (3 * NQ + NW); }
  const float4 val = ((const float4*)src)[off];
  short4v o;
  o.x = f2bf(val.x); o.y = f2bf(val.y); o.z = f2bf(val.z); o.w = f2bf(val.w);
  ((short4v*)dst)[i] = o;
}

// ---------------- 128x128 bf16 GEMM core: C = A (M,K) * B(N,K)^T ----------------
// 4 waves, each owns a 64x64 quadrant as 4x4 16x16 fragments.
// BK=64. Staged via global_load_lds width-16 with XOR chunk swizzle:
// LDS row r, chunk c holds global chunk c^(r&7)  (chunk = 16B = 8 bf16)
// -> ds_read_b128 fragment reads are ~2-way banked (free) instead of 16-way.
__device__ __forceinline__ void gemm128_core(
    const short* __restrict__ A, const short* __restrict__ B,
    const int K, const int m0, const int n0,
    short* lds, f32x4 acc[4][4])
{
  const int t = threadIdx.x;
  const int lane = t & 63;
  const int w = t >> 6;
  const int wr = w >> 1, wc = w & 1;
  const int lr = lane & 15, g = lane >> 4;
  short* As = lds;
  short* Bs = lds + 128 * 64;

#pragma unroll
  for (int i = 0; i < 4; ++i)
#pragma unroll
    for (int j = 0; j < 4; ++j)
      acc[i][j] = (f32x4){0.f, 0.f, 0.f, 0.f};

  const int nkt = K >> 6;
  for (int kt = 0; kt < nkt; ++kt) {
    // stage 16KB A + 16KB B (4 rounds x 256 lanes x 16B each)
#pragma unroll
    for (int j = 0; j < 4; ++j) {
      const int ci = j * 256 + t;            // chunk index 0..1023
      const int r  = ci >> 3;                // tile row 0..127
      const int cs = (ci & 7) ^ (r & 7);     // pre-swizzled source chunk
      const int64_t goff = (int64_t)r * K + kt * 64 + cs * 8;
      const int lbase = (j * 256 + w * 64) * 8;  // wave-uniform LDS base (elems)
      __builtin_amdgcn_global_load_lds(
          (const __attribute__((address_space(1))) void*)(A + (int64_t)m0 * K + goff),
          (__attribute__((address_space(3))) void*)(As + lbase), 16, 0, 0);
      __builtin_amdgcn_global_load_lds(
          (const __attribute__((address_space(1))) void*)(B + (int64_t)n0 * K + goff),
          (__attribute__((address_space(3))) void*)(Bs + lbase), 16, 0, 0);
    }
    __syncthreads();   // compiler emits vmcnt(0) drain before barrier
#pragma unroll
    for (int kk = 0; kk < 2; ++kk) {
      short8v af[4], bfr[4];
#pragma unroll
      for (int mt = 0; mt < 4; ++mt) {
        const int r  = wr * 64 + mt * 16 + lr;
        const int ch = (kk * 4 + g) ^ (r & 7);
        af[mt] = *(const short8v*)(As + r * 64 + ch * 8);
      }
#pragma unroll
      for (int nt = 0; nt < 4; ++nt) {
        const int r  = wc * 64 + nt * 16 + lr;
        const int ch = (kk * 4 + g) ^ (r & 7);
        bfr[nt] = *(const short8v*)(Bs + r * 64 + ch * 8);
      }
#pragma unroll
      for (int mt = 0; mt < 4; ++mt)
#pragma unroll
        for (int nt = 0; nt < 4; ++nt)
          acc[mt][nt] = __builtin_amdgcn_mfma_f32_16x16x32_bf16(
              af[mt], bfr[nt], acc[mt][nt], 0, 0, 0);
    }
    __syncthreads();
  }
}

// ---------------- q/k/v projection (batched over grid.z) ----------------
// z=0 -> qp (row-major bf16), z=1 -> kp (row-major), z=2 -> vpT (transposed [E][S])
__global__ __launch_bounds__(256) void proj_gemm(
    const short* __restrict__ qkv_bf, const short* __restrict__ win_bf,
    const float* __restrict__ in_b,
    short* __restrict__ qp, short* __restrict__ kp, short* __restrict__ vpT)
{
  __shared__ short lds[128 * 64 * 2];
  const int z  = blockIdx.z;
  const int m0 = blockIdx.y * 128;
  const int n0 = blockIdx.x * 128;
  const short* A = qkv_bf + (int64_t)z * L_DIM * E_DIM;
  const short* B = win_bf + (int64_t)z * E_DIM * E_DIM;
  const float* bias = in_b + z * E_DIM;
  f32x4 acc[4][4];
  gemm128_core(A, B, E_DIM, m0, n0, lds, acc);

  const int lane = threadIdx.x & 63;
  const int w = threadIdx.x >> 6;
  const int wr = w >> 1, wc = w & 1;
  const int lr = lane & 15, g = lane >> 4;

  if (z == 2) {
    // MFMA C-layout: lane holds rows (g*4..g*4+3) of a fixed column ->
    // transposed write is a packed 8B store. vpT[col][row..row+3]
#pragma unroll
    for (int nt = 0; nt < 4; ++nt) {
      const int col = n0 + wc * 64 + nt * 16 + lr;
      const float bv = bias[col];
#pragma unroll
      for (int mt = 0; mt < 4; ++mt) {
        const int row = m0 + wr * 64 + mt * 16 + g * 4;
        short4v o;
#pragma unroll
        for (int i = 0; i < 4; ++i) o[i] = f2bf(acc[mt][nt][i] + bv);
        *(short4v*)(vpT + (int64_t)col * S_DIM + row) = o;
      }
    }
  } else {
    short* outp = (z == 0) ? qp : kp;
#pragma unroll
    for (int nt = 0; nt < 4; ++nt) {
      const int col = n0 + wc * 64 + nt * 16 + lr;
      const float bv = bias[col];
#pragma unroll
      for (int mt = 0; mt < 4; ++mt) {
        const int row = m0 + wr * 64 + mt * 16 + g * 4;
#pragma unroll
        for (int i = 0; i < 4; ++i)
          outp[(int64_t)(row + i) * E_DIM + col] = f2bf(acc[mt][nt][i] + bv);
      }
    }
  }
}

// ---------------- out-proj GEMM + bias + residual (fp32 out) ----------------
__global__ __launch_bounds__(256) void outproj_gemm(
    const short* __restrict__ ctx, const short* __restrict__ wout_bf,
    const float* __restrict__ out_b, const float* __restrict__ resid,
    float* __restrict__ res)
{
  __shared__ short lds[128 * 64 * 2];
  const int m0 = blockIdx.y * 128;
  const int n0 = blockIdx.x * 128;
  f32x4 acc[4][4];
  gemm128_core(ctx, wout_bf, E_DIM, m0, n0, lds, acc);

  const int lane = threadIdx.x & 63;
  const int w = threadIdx.x >> 6;
  const int wr = w >> 1, wc = w & 1;
  const int lr = lane & 15, g = lane >> 4;
#pragma unroll
  for (int nt = 0; nt < 4; ++nt) {
    const int col = n0 + wc * 64 + nt * 16 + lr;
    const float bv = out_b[col];
#pragma unroll
    for (int mt = 0; mt < 4; ++mt) {
      const int row = m0 + wr * 64 + mt * 16 + g * 4;
#pragma unroll
      for (int i = 0; i < 4; ++i)
        res[(int64_t)(row + i) * E_DIM + col] =
            acc[mt][nt][i] + bv + resid[(int64_t)(row + i) * E_DIM + col];
    }
  }
}

// ---------------- flash attention ----------------
// NOTE: the reference's type-bias is constant along the softmax axis ->
// softmax is exactly shift-invariant to it -> skipped entirely.
// Swapped QK^T: S^T = mfma(K_frag, Q_frag) puts softmax stats on lane&15,
// which is also the ctx^T accumulator's l-key -> shuffle-free rescale.
__global__ __launch_bounds__(256) void attn_kernel(
    const short* __restrict__ qp, const short* __restrict__ kp,
    const short* __restrict__ vpT, short* __restrict__ ctx)
{
  const int t = threadIdx.x;
  const int lane = t & 63;
  const int w = t >> 6;
  const int h = blockIdx.y;
  const int l0 = blockIdx.x * 64 + w * 16;   // 16 q-rows per wave
  const int lr = lane & 15, g = lane >> 4;

  // Q fragment (B-operand of swapped QK^T): lane holds Q[l0+lr, g*8..+8 (+32)]
  const short* qrow = qp + (int64_t)(l0 + lr) * E_DIM + h * D_DIM + g * 8;
  const short8v qa0 = *(const short8v*)qrow;
  const short8v qa1 = *(const short8v*)(qrow + 32);

  f32x4 acc[4];
#pragma unroll
  for (int b = 0; b < 4; ++b) acc[b] = (f32x4){0.f, 0.f, 0.f, 0.f};
  float m = -1e30f, lsum = 0.f;
  const float scl = 0.18033688011112042f;  // log2(e) / sqrt(D)

  for (int s0 = 0; s0 < S_DIM; s0 += 16) {
    const short* krow = kp + (int64_t)(s0 + lr) * E_DIM + h * D_DIM + g * 8;
    const short8v ka0 = *(const short8v*)krow;
    const short8v ka1 = *(const short8v*)(krow + 32);
    f32x4 st = (f32x4){0.f, 0.f, 0.f, 0.f};
    st = __builtin_amdgcn_mfma_f32_16x16x32_bf16(ka0, qa0, st, 0, 0, 0);
    st = __builtin_amdgcn_mfma_f32_16x16x32_bf16(ka1, qa1, st, 0, 0, 0);
    // st[i] = S^T[s0 + g*4 + i, l0 + lr]

    const float sc0 = st[0] * scl, sc1 = st[1] * scl,
                sc2 = st[2] * scl, sc3 = st[3] * scl;
    float mx = fmaxf(fmaxf(sc0, sc1), fmaxf(sc2, sc3));
    mx = fmaxf(mx, __shfl_xor(mx, 16));
    mx = fmaxf(mx, __shfl_xor(mx, 32));
    const float mnew = fmaxf(m, mx);
    const float rfac = exp2f(m - mnew);
    const float p0 = exp2f(sc0 - mnew), p1 = exp2f(sc1 - mnew),
                p2 = exp2f(sc2 - mnew), p3 = exp2f(sc3 - mnew);
    float ps = p0 + p1 + p2 + p3;
    ps += __shfl_xor(ps, 16);
    ps += __shfl_xor(ps, 32);
    lsum = lsum * rfac + ps;
    m = mnew;

    short4v pb;  // B-frag of P^T for 16x16x16 MFMA — falls out of softmax layout
    pb.x = f2bf(p0); pb.y = f2bf(p1); pb.z = f2bf(p2); pb.w = f2bf(p3);

    const short* vbase = vpT + (int64_t)(h * D_DIM + lr) * S_DIM + s0 + g * 4;
#pragma unroll
    for (int b = 0; b < 4; ++b) {
      acc[b][0] *= rfac; acc[b][1] *= rfac;
      acc[b][2] *= rfac; acc[b][3] *= rfac;
      const short4v vb = *(const short4v*)(vbase + (int64_t)b * 16 * S_DIM);
      acc[b] = __builtin_amdgcn_mfma_f32_16x16x16bf16_1k(vb, pb, acc[b], 0, 0, 0);
    }
  }

  const float rinv = 1.0f / lsum;            // lsum keyed on lane&15 == acc's l-key
  short* crow = ctx + (int64_t)(l0 + lr) * E_DIM + h * D_DIM + g * 4;
#pragma unroll
  for (int b = 0; b < 4; ++b) {
    short4v o;
    o.x = f2bf(acc[b][0] * rinv); o.y = f2bf(acc[b][1] * rinv);
    o.z = f2bf(acc[b][2] * rinv); o.w = f2bf(acc[b][3] * rinv);
    *(short4v*)(crow + b * 16) = o;
  }
}

// ---------------- row LayerNorm (E=1024, one block per row) ----------------
__global__ __launch_bounds__(256) void ln_kernel(
    const float* __restrict__ res, const float* __restrict__ lnw,
    const float* __restrict__ lnb, float* __restrict__ out)
{
  const int row = blockIdx.x;
  const int t = threadIdx.x;
  const float4 v = ((const float4*)(res + (int64_t)row * E_DIM))[t];
  float s  = v.x + v.y + v.z + v.w;
  float s2 = v.x * v.x + v.y * v.y + v.z * v.z + v.w * v.w;
#pragma unroll
  for (int off = 32; off >= 1; off >>= 1) {
    s  += __shfl_xor(s, off);
    s2 += __shfl_xor(s2, off);
  }
  __shared__ float red[8];
  const int w = t >> 6;
  if ((t & 63) == 0) { red[w] = s; red[4 + w] = s2; }
  __syncthreads();
  const float S  = red[0] + red[1] + red[2] + red[3];
  const float S2 = red[4] + red[5] + red[6] + red[7];
  const float mu = S * (1.0f / E_DIM);
  const float rstd = rsqrtf(S2 * (1.0f / E_DIM) - mu * mu + 1e-5f);
  const float4 wv = ((const float4*)lnw)[t];
  const float4 bv = ((const float4*)lnb)[t];
  float4 o;
  o.x = (v.x - mu) * rstd * wv.x + bv.x;
  o.y = (v.y - mu) * rstd * wv.y + bv.y;
  o.z = (v.z - mu) * rstd * wv.z + bv.z;
  o.w = (v.w - mu) * rstd * wv.w + bv.w;
  ((float4*)(out + (int64_t)row * E_DIM))[t] = o;
}

extern "C" void kernel_launch(void* const* d_in, const int* in_sizes, int n_in,
                              void* d_out, int out_size, void* d_ws, size_t ws_size,
                              hipStream_t stream)
{
  const float* q     = (const float*)d_in[0];
  const float* k     = (const float*)d_in[1];
  const float* v     = (const float*)d_in[2];
  // d_in[3] type_weights, d_in[4] time_emb: provably no-ops (softmax shift
  // invariance / unused in reference) — skipped.
  const float* winw  = (const float*)d_in[5];
  const float* winb  = (const float*)d_in[6];
  const float* woutw = (const float*)d_in[7];
  const float* woutb = (const float*)d_in[8];
  // d_in[9..12] time_proj_w/b, type_bias_w/b: unused / no-op.
  const float* lnw   = (const float*)d_in[13];
  const float* lnb   = (const float*)d_in[14];

  short* ws = (short*)d_ws;
  const int64_t LE = (int64_t)L_DIM * E_DIM;   // 2097152
  const int64_t EE = (int64_t)E_DIM * E_DIM;   // 1048576
  short* qkv_bf  = ws;                 // 3*LE bf16 (contiguous with weights below)
  short* win_bf  = ws + 3 * LE;        // 3*EE
  short* wout_bf = win_bf + 3 * EE;    // EE
  short* qp      = wout_bf + EE;       // LE   (L,H,D) row-major
  short* kp      = qp + LE;            // LE   (S,H,D) row-major
  short* vpT     = kp + LE;            // LE   (E,S)   transposed
  short* ctx     = vpT + LE;           // LE   (L,E)   row-major
  float* res     = (float*)(ctx + LE); // LE fp32     (~44 MB total ws use)

  convert_all<<<10240, 256, 0, stream>>>(q, k, v, winw, woutw, qkv_bf);
  proj_gemm<<<dim3(8, 16, 3), 256, 0, stream>>>(qkv_bf, win_bf, winb, qp, kp, vpT);
  attn_kernel<<<dim3(32, 16), 256, 0, stream>>>(qp, kp, vpT, ctx);
  outproj_gemm<<<dim3(8, 16), 256, 0, stream>>>(ctx, wout_bf, woutb, q, res);
  ln_kernel<<<L_DIM, 256, 0, stream>>>(res, lnw, lnb, (float*)d_out);
}